// Round 2
// baseline (28399.878 us; speedup 1.0000x reference)
//
#include <hip/hip_runtime.h>

typedef __attribute__((ext_vector_type(8))) short short8;
typedef __attribute__((ext_vector_type(4))) float floatx4;

// ---------- helpers ----------
__device__ __forceinline__ unsigned short f2bf(float f) {
  unsigned int u = __float_as_uint(f);
  unsigned int lsb = (u >> 16) & 1u;
  u += 0x7fffu + lsb;  // round-to-nearest-even
  return (unsigned short)(u >> 16);
}
__device__ __forceinline__ float bf2f(unsigned short u) {
  unsigned int x = ((unsigned int)u) << 16;
  return __uint_as_float(x);
}
__device__ __forceinline__ float sigm(float x) { return 1.f / (1.f + __expf(-x)); }
__device__ __forceinline__ float tanh_fast(float x) { return 2.f / (1.f + __expf(-2.f * x)) - 1.f; }
__device__ __forceinline__ floatx4 mfma16(short8 a, short8 b, floatx4 c) {
  return __builtin_amdgcn_mfma_f32_16x16x32_bf16(a, b, c, 0, 0, 0);
}

// ---------- prep ----------
// Wc = Wih0 @ in_W (fold layer_in into layer-0 input GEMM); bc = Wih0@in_b + bih0 + bhh0
__global__ void wc_kernel(const float* __restrict__ Wih0, const float* __restrict__ inW,
                          const float* __restrict__ inb, const float* __restrict__ bih0,
                          const float* __restrict__ bhh0, unsigned short* __restrict__ Wc,
                          float* __restrict__ bc) {
  const int n = blockIdx.x;   // 0..1023
  const int k = threadIdx.x;  // 0..127
  float a = 0.f;
  for (int j = 0; j < 256; ++j) a += Wih0[n * 256 + j] * inW[j * 128 + k];
  Wc[n * 128 + k] = f2bf(a);
  if (k == 0) {
    float bsum = bih0[n] + bhh0[n];
    for (int j = 0; j < 256; ++j) bsum += Wih0[n * 256 + j] * inb[j];
    bc[n] = bsum;
  }
}

__global__ void cvt_kernel(unsigned short* __restrict__ dst, const float* __restrict__ src, int n) {
  int i = blockIdx.x * 256 + threadIdx.x;
  if (i < n) dst[i] = f2bf(src[i]);
}

__global__ void addb_kernel(float* __restrict__ b1, const float* __restrict__ xa,
                            const float* __restrict__ ya, int n) {
  int i = blockIdx.x * 256 + threadIdx.x;
  if (i < n) b1[i] = xa[i] + ya[i];
}

// ---------- BatchNorm + spatial attention ----------
__global__ __launch_bounds__(128) void bnsa_kernel(
    const float* __restrict__ x, const float* __restrict__ gamma,
    const float* __restrict__ beta, const float* __restrict__ mean,
    const float* __restrict__ var, const float* __restrict__ saW,
    const float* __restrict__ sab, unsigned short* __restrict__ xs, int rowsPerWg) {
  __shared__ unsigned short saT[128 * 128];  // bf16, [k][j] = saW[j][k]  (33KB total LDS)
  __shared__ float xbuf[128];
  __shared__ float ebuf[128];
  const int j = threadIdx.x;
  for (int k = 0; k < 128; ++k) saT[k * 128 + j] = f2bf(saW[j * 128 + k]);
  const float g = gamma[j], bt = beta[j], mn = mean[j];
  const float istd = rsqrtf(var[j] + 1e-5f);
  const float sb = sab[j];
  __syncthreads();
  const long row0 = (long)blockIdx.x * rowsPerWg;
  for (int it = 0; it < rowsPerWg; ++it) {
    const long row = row0 + it;
    const float xv = x[row * 128 + j];
    const float xb = (xv - mn) * istd * g + bt;
    xbuf[j] = xb;
    __syncthreads();
    float s = sb;
#pragma unroll 8
    for (int k = 0; k < 128; ++k) s += xbuf[k] * bf2f(saT[k * 128 + j]);
    const float e = __expf(sigm(s));
    ebuf[j] = e;
    __syncthreads();
    float sum = 0.f;
#pragma unroll 8
    for (int k = 0; k < 128; ++k) sum += ebuf[k];
    xs[row * 128 + j] = f2bf(xb * (e / sum));
    __syncthreads();
  }
}

// ---------- generic MFMA GEMM: C[M,N] = A[M,K]bf16 @ W[N,K]bf16^T + bias, opt relu ----------
__global__ __launch_bounds__(256) void gemm_bt(
    const unsigned short* __restrict__ A, const unsigned short* __restrict__ W,
    const float* __restrict__ bias, float* __restrict__ Cf,
    unsigned short* __restrict__ Cb, int M, int N, int K, int relu) {
  __shared__ unsigned short As[128 * 32];
  __shared__ unsigned short Ws[128 * 32];
  const int tid = threadIdx.x;
  const int wv = tid >> 6, lane = tid & 63;
  const int lm = lane & 15, q = lane >> 4;
  const int mh = (wv & 1) * 64, nh = (wv >> 1) * 64;
  const long m0 = (long)blockIdx.x * 128;
  const long n0 = (long)blockIdx.y * 128;

  floatx4 acc[16];
#pragma unroll
  for (int i = 0; i < 16; ++i) acc[i] = (floatx4){0.f, 0.f, 0.f, 0.f};

  for (int k0 = 0; k0 < K; k0 += 32) {
#pragma unroll
    for (int i = 0; i < 2; ++i) {
      const int c = tid + i * 256;
      const int row = c >> 2, off = (c & 3) * 8;
      *(short8*)&As[row * 32 + off] = *(const short8*)&A[(m0 + row) * K + k0 + off];
      *(short8*)&Ws[row * 32 + off] = *(const short8*)&W[(n0 + row) * K + k0 + off];
    }
    __syncthreads();
    short8 af[4], wf[4];
#pragma unroll
    for (int a = 0; a < 4; ++a) af[a] = *(const short8*)&As[(mh + a * 16 + lm) * 32 + q * 8];
#pragma unroll
    for (int b = 0; b < 4; ++b) wf[b] = *(const short8*)&Ws[(nh + b * 16 + lm) * 32 + q * 8];
#pragma unroll
    for (int a = 0; a < 4; ++a)
#pragma unroll
      for (int b = 0; b < 4; ++b) acc[a * 4 + b] = mfma16(af[a], wf[b], acc[a * 4 + b]);
    __syncthreads();
  }
#pragma unroll
  for (int a = 0; a < 4; ++a)
#pragma unroll
    for (int b = 0; b < 4; ++b)
#pragma unroll
      for (int r = 0; r < 4; ++r) {
        const long m = m0 + mh + a * 16 + q * 4 + r;  // C/D: row = quad*4+reg
        const long n = n0 + nh + b * 16 + lm;         //      col = lane&15
        float v = acc[a * 4 + b][r] + bias[n];
        if (relu) v = fmaxf(v, 0.f);
        if (Cf) Cf[m * N + n] = v;
        if (Cb) Cb[m * N + n] = f2bf(v);
      }
}

// ---------- Plan A: persistent LSTM recurrence (G materialized) ----------
__global__ __launch_bounds__(256, 1) void rec_kernel(
    const unsigned short* __restrict__ Whh,  // [1024,256] bf16
    const float* __restrict__ Gf,            // [B,T,1024] f32 (or null)
    const unsigned short* __restrict__ Gh,   // [B,T,1024] bf16 (or null)
    unsigned short* __restrict__ hs) {       // [B,T,256] bf16
  __shared__ unsigned short hbuf[16 * 264];
  const int tid = threadIdx.x;
  const int wv = tid >> 6, lane = tid & 63;
  const int lm = lane & 15, q = lane >> 4;
  const int b0 = blockIdx.x * 16;
  const int col = wv * 16 + lm;

  for (int i = tid; i < 16 * 264; i += 256) hbuf[i] = 0;

  floatx4 cst[4];
#pragma unroll
  for (int i = 0; i < 4; ++i) cst[i] = (floatx4){0.f, 0.f, 0.f, 0.f};

  float gbuf[64];
#pragma unroll
  for (int ci = 0; ci < 16; ++ci)
#pragma unroll
    for (int r = 0; r < 4; ++r) {
      const long gi = ((long)(b0 + q * 4 + r) * 512) * 1024 + ci * 64 + col;
      gbuf[ci * 4 + r] = Gf ? Gf[gi] : bf2f(Gh[gi]);
    }
  __syncthreads();

  for (int t = 0; t < 512; ++t) {
    short8 af[8];
#pragma unroll
    for (int kt = 0; kt < 8; ++kt) af[kt] = *(const short8*)&hbuf[lm * 264 + kt * 32 + q * 8];

    floatx4 acc[16];
#pragma unroll
    for (int ci = 0; ci < 16; ++ci)
      acc[ci] = (floatx4){gbuf[ci * 4 + 0], gbuf[ci * 4 + 1], gbuf[ci * 4 + 2], gbuf[ci * 4 + 3]};

    const int tn = (t < 511) ? t + 1 : t;  // prefetch next G
#pragma unroll
    for (int ci = 0; ci < 16; ++ci)
#pragma unroll
      for (int r = 0; r < 4; ++r) {
        const long gi = ((long)(b0 + q * 4 + r) * 512 + tn) * 1024 + ci * 64 + col;
        gbuf[ci * 4 + r] = Gf ? Gf[gi] : bf2f(Gh[gi]);
      }

    const unsigned short* wbase = Whh + (size_t)col * 256 + q * 8;
    short8 bfr[2][8];
#pragma unroll
    for (int kt = 0; kt < 8; ++kt) bfr[0][kt] = *(const short8*)(wbase + kt * 32);
#pragma unroll
    for (int ci = 0; ci < 16; ++ci) {
      const int cur = ci & 1, nxt = cur ^ 1;
      if (ci < 15) {
        const unsigned short* wn = wbase + (size_t)(ci + 1) * (64 * 256);
#pragma unroll
        for (int kt = 0; kt < 8; ++kt) bfr[nxt][kt] = *(const short8*)(wn + kt * 32);
      }
      floatx4 a = acc[ci];
#pragma unroll
      for (int kt = 0; kt < 8; ++kt) a = mfma16(af[kt], bfr[cur][kt], a);
      acc[ci] = a;
    }

    float hnv[16];
#pragma unroll
    for (int ci = 0; ci < 4; ++ci)
#pragma unroll
      for (int r = 0; r < 4; ++r) {
        const float iv = acc[ci][r], fv = acc[ci + 4][r], gv = acc[ci + 8][r], ov = acc[ci + 12][r];
        const float cn = sigm(fv) * cst[ci][r] + sigm(iv) * tanh_fast(gv);
        cst[ci][r] = cn;
        const float hn = sigm(ov) * tanh_fast(cn);
        hnv[ci * 4 + r] = hn;
        hs[((long)(b0 + q * 4 + r) * 512 + t) * 256 + ci * 64 + col] = f2bf(hn);
      }
    __syncthreads();
#pragma unroll
    for (int ci = 0; ci < 4; ++ci)
#pragma unroll
      for (int r = 0; r < 4; ++r)
        hbuf[(q * 4 + r) * 264 + ci * 64 + col] = f2bf(hnv[ci * 4 + r]);
    __syncthreads();
  }
}

// ---------- Plan A: temporal attention + output ----------
__global__ __launch_bounds__(128) void temporal_kernel(
    const float* __restrict__ total, const float* __restrict__ spre,
    const float* __restrict__ outW, float* __restrict__ out) {
  __shared__ float red[128];
  const int f = threadIdx.x;
  const long b = blockIdx.x;
  float num = 0.f, den = 0.f;
  for (int t = 0; t < 512; ++t) {
    const long idx = (b * 512 + t) * 128 + f;
    const float e = __expf(spre[idx]);  // spre = relu(..) in [0, ~1]: no overflow
    num += e * total[idx];
    den += e;
  }
  red[f] = (num / den) * outW[f];
  __syncthreads();
  if (f == 0) {
    float s = 0.f;
    for (int k = 0; k < 128; ++k) s += red[k];
    out[b] = s;
  }
}

// ---------- Plan C: fully fused persistent kernel (both LSTM layers + temporal attn) ----------
// 16 wgs x 256 thr, wg owns 16 batch rows for all 512 steps. Needs only xs (+weights) in ws.
__global__ __launch_bounds__(256, 1) void mega_kernel(
    const unsigned short* __restrict__ xs,    // [B,T,128] bf16
    const unsigned short* __restrict__ Wc, const float* __restrict__ bc,
    const unsigned short* __restrict__ Whh0,
    const unsigned short* __restrict__ Wih1, const float* __restrict__ b1,
    const unsigned short* __restrict__ Whh1,
    const unsigned short* __restrict__ tahWg, const float* __restrict__ tahb,
    const unsigned short* __restrict__ taWg, const float* __restrict__ tab,
    const float* __restrict__ outW, float* __restrict__ out) {
  __shared__ unsigned short h0buf[16 * 264];
  __shared__ unsigned short h1buf[16 * 264];
  __shared__ float totF[16 * 128];
  __shared__ unsigned short totB[16 * 136];
  __shared__ unsigned short tahWs[128 * 264];  // [f][k] k=0..255
  __shared__ unsigned short taWs[128 * 136];   // [f][j] j=0..127
  __shared__ float red[16 * 68];

  const int tid = threadIdx.x;
  const int wv = tid >> 6, lane = tid & 63;
  const int lm = lane & 15, q = lane >> 4;
  const int b0 = blockIdx.x * 16;
  const int col = wv * 16 + lm;  // 0..63

  for (int i = tid; i < 16 * 264; i += 256) { h0buf[i] = 0; h1buf[i] = 0; }
  for (int i = tid; i < 128 * 256; i += 256) tahWs[(i >> 8) * 264 + (i & 255)] = tahWg[i];
  for (int i = tid; i < 128 * 128; i += 256) taWs[(i >> 7) * 136 + (i & 127)] = taWg[i];

  float bc0v[16], b1v[16];
#pragma unroll
  for (int ci = 0; ci < 16; ++ci) { bc0v[ci] = bc[ci * 64 + col]; b1v[ci] = b1[ci * 64 + col]; }
  float tahbv[2], tabv[2], outWv[2];
#pragma unroll
  for (int c = 0; c < 2; ++c) {
    tahbv[c] = tahb[c * 64 + col];
    tabv[c] = tab[c * 64 + col];
    outWv[c] = outW[c * 64 + col];
  }

  floatx4 cst0[4], cst1[4];
#pragma unroll
  for (int i = 0; i < 4; ++i) { cst0[i] = (floatx4){0.f, 0.f, 0.f, 0.f}; cst1[i] = cst0[i]; }
  float num[8], den[8];
#pragma unroll
  for (int i = 0; i < 8; ++i) { num[i] = 0.f; den[i] = 0.f; }

  const unsigned short* xrow = xs + (size_t)(b0 + lm) * 512 * 128 + q * 8;
  short8 axf[4];
#pragma unroll
  for (int kt = 0; kt < 4; ++kt) axf[kt] = *(const short8*)(xrow + kt * 32);

  const unsigned short* wcb = Wc + (size_t)col * 128 + q * 8;
  const unsigned short* w0b = Whh0 + (size_t)col * 256 + q * 8;
  const unsigned short* w1i = Wih1 + (size_t)col * 256 + q * 8;
  const unsigned short* w1h = Whh1 + (size_t)col * 256 + q * 8;

  __syncthreads();

  for (int t = 0; t < 512; ++t) {
    // ---- gates0 = xs_t @ Wc^T + h0 @ Whh0^T + bc ----
    short8 a0f[8];
#pragma unroll
    for (int kt = 0; kt < 8; ++kt) a0f[kt] = *(const short8*)&h0buf[lm * 264 + kt * 32 + q * 8];

    short8 wf[2][12];
#pragma unroll
    for (int kt = 0; kt < 4; ++kt) wf[0][kt] = *(const short8*)(wcb + kt * 32);
#pragma unroll
    for (int kt = 0; kt < 8; ++kt) wf[0][4 + kt] = *(const short8*)(w0b + kt * 32);

    floatx4 acc[16];
#pragma unroll
    for (int ci = 0; ci < 16; ++ci) acc[ci] = (floatx4){bc0v[ci], bc0v[ci], bc0v[ci], bc0v[ci]};
#pragma unroll
    for (int ci = 0; ci < 16; ++ci) {
      const int cur = ci & 1, nxt = cur ^ 1;
      if (ci < 15) {
        const unsigned short* pc = wcb + (size_t)(ci + 1) * (64 * 128);
        const unsigned short* p0 = w0b + (size_t)(ci + 1) * (64 * 256);
#pragma unroll
        for (int kt = 0; kt < 4; ++kt) wf[nxt][kt] = *(const short8*)(pc + kt * 32);
#pragma unroll
        for (int kt = 0; kt < 8; ++kt) wf[nxt][4 + kt] = *(const short8*)(p0 + kt * 32);
      }
      floatx4 a = acc[ci];
#pragma unroll
      for (int kt = 0; kt < 4; ++kt) a = mfma16(axf[kt], wf[cur][kt], a);
#pragma unroll
      for (int kt = 0; kt < 8; ++kt) a = mfma16(a0f[kt], wf[cur][4 + kt], a);
      acc[ci] = a;
    }

    // ---- cell0 ----
    float h0v[16];
#pragma unroll
    for (int ci = 0; ci < 4; ++ci)
#pragma unroll
      for (int r = 0; r < 4; ++r) {
        const float iv = acc[ci][r], fv = acc[ci + 4][r], gv = acc[ci + 8][r], ov = acc[ci + 12][r];
        const float cn = sigm(fv) * cst0[ci][r] + sigm(iv) * tanh_fast(gv);
        cst0[ci][r] = cn;
        h0v[ci * 4 + r] = sigm(ov) * tanh_fast(cn);
      }
    __syncthreads();  // all waves done reading h0buf
#pragma unroll
    for (int ci = 0; ci < 4; ++ci)
#pragma unroll
      for (int r = 0; r < 4; ++r)
        h0buf[(q * 4 + r) * 264 + ci * 64 + col] = f2bf(h0v[ci * 4 + r]);
    __syncthreads();  // h0_t visible

    // ---- gates1 = h0_t @ Wih1^T + h1 @ Whh1^T + b1 ----
    short8 a0n[8], a1f[8];
#pragma unroll
    for (int kt = 0; kt < 8; ++kt) {
      a0n[kt] = *(const short8*)&h0buf[lm * 264 + kt * 32 + q * 8];
      a1f[kt] = *(const short8*)&h1buf[lm * 264 + kt * 32 + q * 8];
    }
    short8 wg[2][16];
#pragma unroll
    for (int kt = 0; kt < 8; ++kt) {
      wg[0][kt] = *(const short8*)(w1i + kt * 32);
      wg[0][8 + kt] = *(const short8*)(w1h + kt * 32);
    }
#pragma unroll
    for (int ci = 0; ci < 16; ++ci) acc[ci] = (floatx4){b1v[ci], b1v[ci], b1v[ci], b1v[ci]};
#pragma unroll
    for (int ci = 0; ci < 16; ++ci) {
      const int cur = ci & 1, nxt = cur ^ 1;
      if (ci < 15) {
        const unsigned short* pi = w1i + (size_t)(ci + 1) * (64 * 256);
        const unsigned short* ph = w1h + (size_t)(ci + 1) * (64 * 256);
#pragma unroll
        for (int kt = 0; kt < 8; ++kt) {
          wg[nxt][kt] = *(const short8*)(pi + kt * 32);
          wg[nxt][8 + kt] = *(const short8*)(ph + kt * 32);
        }
      }
      floatx4 a = acc[ci];
#pragma unroll
      for (int kt = 0; kt < 8; ++kt) a = mfma16(a0n[kt], wg[cur][kt], a);
#pragma unroll
      for (int kt = 0; kt < 8; ++kt) a = mfma16(a1f[kt], wg[cur][8 + kt], a);
      acc[ci] = a;
    }

    // ---- cell1 ----
    float h1v[16];
#pragma unroll
    for (int ci = 0; ci < 4; ++ci)
#pragma unroll
      for (int r = 0; r < 4; ++r) {
        const float iv = acc[ci][r], fv = acc[ci + 4][r], gv = acc[ci + 8][r], ov = acc[ci + 12][r];
        const float cn = sigm(fv) * cst1[ci][r] + sigm(iv) * tanh_fast(gv);
        cst1[ci][r] = cn;
        h1v[ci * 4 + r] = sigm(ov) * tanh_fast(cn);
      }
    __syncthreads();  // a1f reads done
#pragma unroll
    for (int ci = 0; ci < 4; ++ci)
#pragma unroll
      for (int r = 0; r < 4; ++r)
        h1buf[(q * 4 + r) * 264 + ci * 64 + col] = f2bf(h1v[ci * 4 + r]);
    __syncthreads();  // h1_t visible

    // ---- total_t = h1_t @ tahW^T + tahb ----
    short8 a1n[8];
#pragma unroll
    for (int kt = 0; kt < 8; ++kt) a1n[kt] = *(const short8*)&h1buf[lm * 264 + kt * 32 + q * 8];
    floatx4 tacc[2];
#pragma unroll
    for (int cit = 0; cit < 2; ++cit) {
      floatx4 a = (floatx4){tahbv[cit], tahbv[cit], tahbv[cit], tahbv[cit]};
#pragma unroll
      for (int kt = 0; kt < 8; ++kt)
        a = mfma16(a1n[kt], *(const short8*)&tahWs[(cit * 64 + col) * 264 + kt * 32 + q * 8], a);
      tacc[cit] = a;
    }
#pragma unroll
    for (int cit = 0; cit < 2; ++cit)
#pragma unroll
      for (int r = 0; r < 4; ++r) {
        totF[(q * 4 + r) * 128 + cit * 64 + col] = tacc[cit][r];
        totB[(q * 4 + r) * 136 + cit * 64 + col] = f2bf(tacc[cit][r]);
      }
    __syncthreads();  // tot visible

    // ---- spre = relu(total @ taW^T + tab); accumulate softmax-over-t numer/denom ----
    short8 atf[4];
#pragma unroll
    for (int kt = 0; kt < 4; ++kt) atf[kt] = *(const short8*)&totB[lm * 136 + kt * 32 + q * 8];
#pragma unroll
    for (int cit = 0; cit < 2; ++cit) {
      floatx4 s = (floatx4){tabv[cit], tabv[cit], tabv[cit], tabv[cit]};
#pragma unroll
      for (int kt = 0; kt < 4; ++kt)
        s = mfma16(atf[kt], *(const short8*)&taWs[(cit * 64 + col) * 136 + kt * 32 + q * 8], s);
#pragma unroll
      for (int r = 0; r < 4; ++r) {
        const float e = __expf(fmaxf(s[r], 0.f));
        num[cit * 4 + r] += e * totF[(q * 4 + r) * 128 + cit * 64 + col];
        den[cit * 4 + r] += e;
      }
    }

    // prefetch next xs A-frags
    const int tn = (t < 511) ? t + 1 : t;
#pragma unroll
    for (int kt = 0; kt < 4; ++kt) axf[kt] = *(const short8*)(xrow + (size_t)tn * 128 + kt * 32);
  }

  // ---- out[b] = sum_f (num/den)*outW ----
#pragma unroll
  for (int r = 0; r < 4; ++r) {
    float v = 0.f;
#pragma unroll
    for (int cit = 0; cit < 2; ++cit) v += (num[cit * 4 + r] / den[cit * 4 + r]) * outWv[cit];
    red[(q * 4 + r) * 68 + col] = v;
  }
  __syncthreads();
  if (tid < 16) {
    float s = 0.f;
    for (int k = 0; k < 64; ++k) s += red[tid * 68 + k];
    out[b0 + tid] = s;
  }
}

// ---------- host ----------
extern "C" void kernel_launch(void* const* d_in, const int* in_sizes, int n_in,
                              void* d_out, int out_size, void* d_ws, size_t ws_size,
                              hipStream_t stream) {
  (void)in_sizes; (void)n_in; (void)out_size;
  const float* x    = (const float*)d_in[0];
  const float* bng  = (const float*)d_in[1];
  const float* bnb  = (const float*)d_in[2];
  const float* bnm  = (const float*)d_in[3];
  const float* bnv  = (const float*)d_in[4];
  const float* saW  = (const float*)d_in[5];
  const float* sab  = (const float*)d_in[6];
  const float* inW  = (const float*)d_in[7];
  const float* inb  = (const float*)d_in[8];
  const float* Wih0 = (const float*)d_in[9];
  const float* Whh0 = (const float*)d_in[10];
  const float* bih0 = (const float*)d_in[11];
  const float* bhh0 = (const float*)d_in[12];
  const float* Wih1 = (const float*)d_in[13];
  const float* Whh1 = (const float*)d_in[14];
  const float* bih1 = (const float*)d_in[15];
  const float* bhh1 = (const float*)d_in[16];
  const float* tahW = (const float*)d_in[17];
  const float* tahb = (const float*)d_in[18];
  const float* taW  = (const float*)d_in[19];
  const float* tab  = (const float*)d_in[20];
  const float* outW = (const float*)d_in[21];
  float* out = (float*)d_out;

  char* ws = (char*)d_ws;
  size_t off = 0;
  auto alloc = [&](size_t bytes) {
    char* p = ws + off;
    off += (bytes + 255) & ~(size_t)255;
    return p;
  };
  // shared prep buffers (~36 MB incl. xs)
  unsigned short* Wc    = (unsigned short*)alloc((size_t)1024 * 128 * 2);
  float* bc             = (float*)alloc(1024 * 4);
  float* b1             = (float*)alloc(1024 * 4);
  unsigned short* Whh0b = (unsigned short*)alloc((size_t)1024 * 256 * 2);
  unsigned short* Whh1b = (unsigned short*)alloc((size_t)1024 * 256 * 2);
  unsigned short* Wih1b = (unsigned short*)alloc((size_t)1024 * 256 * 2);
  unsigned short* tahWb = (unsigned short*)alloc((size_t)128 * 256 * 2);
  unsigned short* taWb  = (unsigned short*)alloc((size_t)128 * 128 * 2);
  unsigned short* xs    = (unsigned short*)alloc((size_t)131072 * 128 * 2);

  const size_t gF32 = (size_t)131072 * 1024 * 4;
  const size_t gB16 = (size_t)131072 * 1024 * 2;
  const size_t hsB  = (size_t)131072 * 256 * 2;
  const int planAf32 = (off + gF32 + 2 * hsB + 4096) <= ws_size;
  const int planA    = (off + gB16 + 2 * hsB + 4096) <= ws_size;

  // shared prep
  hipLaunchKernelGGL(wc_kernel, dim3(1024), dim3(128), 0, stream, Wih0, inW, inb, bih0, bhh0, Wc, bc);
  hipLaunchKernelGGL(cvt_kernel, dim3(1024), dim3(256), 0, stream, Whh0b, Whh0, 262144);
  hipLaunchKernelGGL(cvt_kernel, dim3(1024), dim3(256), 0, stream, Whh1b, Whh1, 262144);
  hipLaunchKernelGGL(cvt_kernel, dim3(1024), dim3(256), 0, stream, Wih1b, Wih1, 262144);
  hipLaunchKernelGGL(cvt_kernel, dim3(128), dim3(256), 0, stream, tahWb, tahW, 32768);
  hipLaunchKernelGGL(cvt_kernel, dim3(64), dim3(256), 0, stream, taWb, taW, 16384);
  hipLaunchKernelGGL(addb_kernel, dim3(4), dim3(256), 0, stream, b1, bih1, bhh1, 1024);
  hipLaunchKernelGGL(bnsa_kernel, dim3(1024), dim3(128), 0, stream, x, bng, bnb, bnm, bnv, saW, sab, xs, 128);

  if (planA || planAf32) {
    // -------- Plan A: materialized G --------
    char* Gregion = alloc(planAf32 ? gF32 : gB16);
    unsigned short* hs0 = (unsigned short*)alloc(hsB);
    unsigned short* hs1 = (unsigned short*)alloc(hsB);
    float* Gf = planAf32 ? (float*)Gregion : nullptr;
    unsigned short* Gh = planAf32 ? nullptr : (unsigned short*)Gregion;
    // temporal buffers carved from G region (dead after rec1): 67.1+33.6+67.1 MB <= 268 MB
    float* totalF = (float*)Gregion;
    unsigned short* totalB = (unsigned short*)(Gregion + (size_t)131072 * 128 * 4);
    float* spre = (float*)(Gregion + (size_t)131072 * 128 * 4 + (size_t)131072 * 128 * 2);

    hipLaunchKernelGGL(gemm_bt, dim3(1024, 8), dim3(256), 0, stream, xs, Wc, bc, Gf, Gh,
                       131072, 1024, 128, 0);
    hipLaunchKernelGGL(rec_kernel, dim3(16), dim3(256), 0, stream, Whh0b, Gf, Gh, hs0);
    hipLaunchKernelGGL(gemm_bt, dim3(1024, 8), dim3(256), 0, stream, hs0, Wih1b, b1, Gf, Gh,
                       131072, 1024, 256, 0);
    hipLaunchKernelGGL(rec_kernel, dim3(16), dim3(256), 0, stream, Whh1b, Gf, Gh, hs1);
    hipLaunchKernelGGL(gemm_bt, dim3(1024, 1), dim3(256), 0, stream, hs1, tahWb, tahb, totalF,
                       totalB, 131072, 128, 256, 0);
    hipLaunchKernelGGL(gemm_bt, dim3(1024, 1), dim3(256), 0, stream, totalB, taWb, tab, spre,
                       (unsigned short*)nullptr, 131072, 128, 128, 1);
    hipLaunchKernelGGL(temporal_kernel, dim3(256), dim3(128), 0, stream, totalF, spre, outW, out);
  } else {
    // -------- Plan C: fully fused, minimal workspace --------
    hipLaunchKernelGGL(mega_kernel, dim3(16), dim3(256), 0, stream, xs, Wc, bc, Whh0b, Wih1b, b1,
                       Whh1b, tahWb, tahb, taWb, tab, outW, out);
  }
}

// Round 3
// 27125.949 us; speedup vs baseline: 1.0470x; 1.0470x over previous
//
#include <hip/hip_runtime.h>

typedef __attribute__((ext_vector_type(8))) short short8;
typedef __attribute__((ext_vector_type(4))) float floatx4;

// ---------- helpers ----------
__device__ __forceinline__ unsigned short f2bf(float f) {
  unsigned int u = __float_as_uint(f);
  unsigned int lsb = (u >> 16) & 1u;
  u += 0x7fffu + lsb;  // round-to-nearest-even
  return (unsigned short)(u >> 16);
}
__device__ __forceinline__ float bf2f(unsigned short u) {
  unsigned int x = ((unsigned int)u) << 16;
  return __uint_as_float(x);
}
__device__ __forceinline__ float sigm(float x) { return 1.f / (1.f + __expf(-x)); }
__device__ __forceinline__ float tanh_fast(float x) { return 2.f / (1.f + __expf(-2.f * x)) - 1.f; }
__device__ __forceinline__ floatx4 mfma16(short8 a, short8 b, floatx4 c) {
  return __builtin_amdgcn_mfma_f32_16x16x32_bf16(a, b, c, 0, 0, 0);
}

// ---------- prep ----------
// Wc = Wih0 @ in_W (fold layer_in into layer-0 input GEMM); bc = Wih0@in_b + bih0 + bhh0
__global__ void wc_kernel(const float* __restrict__ Wih0, const float* __restrict__ inW,
                          const float* __restrict__ inb, const float* __restrict__ bih0,
                          const float* __restrict__ bhh0, unsigned short* __restrict__ Wc,
                          float* __restrict__ bc) {
  const int n = blockIdx.x;   // 0..1023
  const int k = threadIdx.x;  // 0..127
  float a = 0.f;
  for (int j = 0; j < 256; ++j) a += Wih0[n * 256 + j] * inW[j * 128 + k];
  Wc[n * 128 + k] = f2bf(a);
  if (k == 0) {
    float bsum = bih0[n] + bhh0[n];
    for (int j = 0; j < 256; ++j) bsum += Wih0[n * 256 + j] * inb[j];
    bc[n] = bsum;
  }
}

__global__ void cvt_kernel(unsigned short* __restrict__ dst, const float* __restrict__ src, int n) {
  int i = blockIdx.x * 256 + threadIdx.x;
  if (i < n) dst[i] = f2bf(src[i]);
}

__global__ void addb_kernel(float* __restrict__ b1, const float* __restrict__ xa,
                            const float* __restrict__ ya, int n) {
  int i = blockIdx.x * 256 + threadIdx.x;
  if (i < n) b1[i] = xa[i] + ya[i];
}

// ---------- BatchNorm + spatial attention ----------
__global__ __launch_bounds__(128) void bnsa_kernel(
    const float* __restrict__ x, const float* __restrict__ gamma,
    const float* __restrict__ beta, const float* __restrict__ mean,
    const float* __restrict__ var, const float* __restrict__ saW,
    const float* __restrict__ sab, unsigned short* __restrict__ xs, int rowsPerWg) {
  __shared__ unsigned short saT[128 * 128];  // bf16 [k][j] = saW[j][k]
  __shared__ float xbuf[128];
  __shared__ float ebuf[128];
  const int j = threadIdx.x;
  for (int k = 0; k < 128; ++k) saT[k * 128 + j] = f2bf(saW[j * 128 + k]);
  const float g = gamma[j], bt = beta[j], mn = mean[j];
  const float istd = rsqrtf(var[j] + 1e-5f);
  const float sb = sab[j];
  __syncthreads();
  const long row0 = (long)blockIdx.x * rowsPerWg;
  for (int it = 0; it < rowsPerWg; ++it) {
    const long row = row0 + it;
    const float xv = x[row * 128 + j];
    const float xb = (xv - mn) * istd * g + bt;
    xbuf[j] = xb;
    __syncthreads();
    float s = sb;
#pragma unroll 8
    for (int k = 0; k < 128; ++k) s += xbuf[k] * bf2f(saT[k * 128 + j]);
    const float e = __expf(sigm(s));
    ebuf[j] = e;
    __syncthreads();
    float sum = 0.f;
#pragma unroll 8
    for (int k = 0; k < 128; ++k) sum += ebuf[k];
    xs[row * 128 + j] = f2bf(xb * (e / sum));
    __syncthreads();
  }
}

// ---------- MFMA GEMM: C[M,N] = A[M,K]bf16 @ W[N,K]bf16^T + bias ----------
__global__ __launch_bounds__(256) void gemm_bt(
    const unsigned short* __restrict__ A, const unsigned short* __restrict__ W,
    const float* __restrict__ bias, float* __restrict__ Cf,
    unsigned short* __restrict__ Cb, int M, int N, int K, int relu) {
  __shared__ unsigned short As[128 * 32];
  __shared__ unsigned short Ws[128 * 32];
  const int tid = threadIdx.x;
  const int wv = tid >> 6, lane = tid & 63;
  const int lm = lane & 15, q = lane >> 4;
  const int mh = (wv & 1) * 64, nh = (wv >> 1) * 64;
  const long m0 = (long)blockIdx.x * 128;
  const long n0 = (long)blockIdx.y * 128;

  floatx4 acc[16];
#pragma unroll
  for (int i = 0; i < 16; ++i) acc[i] = (floatx4){0.f, 0.f, 0.f, 0.f};

  for (int k0 = 0; k0 < K; k0 += 32) {
#pragma unroll
    for (int i = 0; i < 2; ++i) {
      const int cc = tid + i * 256;
      const int row = cc >> 2, off = (cc & 3) * 8;
      *(short8*)&As[row * 32 + off] = *(const short8*)&A[(m0 + row) * K + k0 + off];
      *(short8*)&Ws[row * 32 + off] = *(const short8*)&W[(n0 + row) * K + k0 + off];
    }
    __syncthreads();
    short8 af[4], wf[4];
#pragma unroll
    for (int a = 0; a < 4; ++a) af[a] = *(const short8*)&As[(mh + a * 16 + lm) * 32 + q * 8];
#pragma unroll
    for (int b = 0; b < 4; ++b) wf[b] = *(const short8*)&Ws[(nh + b * 16 + lm) * 32 + q * 8];
#pragma unroll
    for (int a = 0; a < 4; ++a)
#pragma unroll
      for (int b = 0; b < 4; ++b) acc[a * 4 + b] = mfma16(af[a], wf[b], acc[a * 4 + b]);
    __syncthreads();
  }
#pragma unroll
  for (int a = 0; a < 4; ++a)
#pragma unroll
    for (int b = 0; b < 4; ++b)
#pragma unroll
      for (int r = 0; r < 4; ++r) {
        const long m = m0 + mh + a * 16 + q * 4 + r;  // C/D: row = quad*4+reg
        const long n = n0 + nh + b * 16 + lm;         //      col = lane&15
        float v = acc[a * 4 + b][r] + bias[n];
        if (relu) v = fmaxf(v, 0.f);
        if (Cf) Cf[m * N + n] = v;
        if (Cb) Cb[m * N + n] = f2bf(v);
      }
}

// ---------- fused persistent kernel, 8 waves/wg ----------
// 16 wgs x 512 thr; wg owns 16 batch rows, wave (c=wv&3, sh=wv>>2) owns hidden cols
// {c*64 + (2*sh+s2)*16 + lm, s2 in 0..1} for both layers (gate quadruples wave-local),
// and attn f-col sh*64 + c*16 + lm. Weights streamed from L2 as direct B-frag loads.
__global__ __launch_bounds__(512, 2) void mega8_kernel(
    const unsigned short* __restrict__ xs,   // [B,T,128] bf16 (used if G0 null)
    const unsigned short* __restrict__ G0,   // [B,T,1024] bf16 = xs@Wc^T+bc, or null
    const unsigned short* __restrict__ Wc, const float* __restrict__ bc,
    const unsigned short* __restrict__ Whh0,
    const unsigned short* __restrict__ Wih1, const float* __restrict__ b1,
    const unsigned short* __restrict__ Whh1,
    const unsigned short* __restrict__ tahWg, const float* __restrict__ tahb,
    const unsigned short* __restrict__ taWg, const float* __restrict__ tab,
    const float* __restrict__ outW, float* __restrict__ out) {
  __shared__ unsigned short h0buf[16 * 264];
  __shared__ unsigned short h1buf[16 * 264];
  __shared__ unsigned short totB[16 * 136];
  __shared__ unsigned short tahWs[128 * 264];  // [f][k], k=0..255
  __shared__ unsigned short taWs[128 * 136];   // [f][j], j=0..127
  __shared__ float red[16 * 136];

  const int tid = threadIdx.x;
  const int wv = tid >> 6, lane = tid & 63;
  const int lm = lane & 15, q = lane >> 4;
  const int c = wv & 3, sh = wv >> 2;
  const int b0 = blockIdx.x * 16;

  for (int i = tid; i < 16 * 264; i += 512) { h0buf[i] = 0; h1buf[i] = 0; }
  for (int i = tid; i < 128 * 256; i += 512) tahWs[(i >> 8) * 264 + (i & 255)] = tahWg[i];
  for (int i = tid; i < 128 * 128; i += 512) taWs[(i >> 7) * 136 + (i & 127)] = taWg[i];

  // gate-block n indices: blk = s2*4+g -> n = g*256 + c*64 + (2*sh+s2)*16 + lm
  int nidx[8];
#pragma unroll
  for (int s2 = 0; s2 < 2; ++s2)
#pragma unroll
    for (int g = 0; g < 4; ++g) nidx[s2 * 4 + g] = g * 256 + c * 64 + (2 * sh + s2) * 16 + lm;

  float bc0v[8], b1v[8];
#pragma unroll
  for (int blk = 0; blk < 8; ++blk) {
    bc0v[blk] = G0 ? 0.f : bc[nidx[blk]];
    b1v[blk] = b1[nidx[blk]];
  }
  const int fb = sh * 64 + c * 16;
  const int fcol = fb + lm;
  const float tahbv = tahb[fcol], tabv = tab[fcol], outWv = outW[fcol];

  floatx4 cst0[2], cst1[2];
#pragma unroll
  for (int i = 0; i < 2; ++i) { cst0[i] = (floatx4){0.f, 0.f, 0.f, 0.f}; cst1[i] = cst0[i]; }
  float num[4] = {0.f, 0.f, 0.f, 0.f}, den[4] = {0.f, 0.f, 0.f, 0.f};

  const unsigned short* xrow = xs + (size_t)(b0 + lm) * 65536 + q * 8;
  __syncthreads();

  for (int t = 0; t < 512; ++t) {
    // ---- layer0: gates = [x-part] + h0 @ Whh0^T ----
    short8 a0f[8];
#pragma unroll
    for (int kt = 0; kt < 8; ++kt) a0f[kt] = *(const short8*)&h0buf[lm * 264 + kt * 32 + q * 8];

    floatx4 acc[8];
    if (G0) {
#pragma unroll
      for (int blk = 0; blk < 8; ++blk)
#pragma unroll
        for (int r = 0; r < 4; ++r)
          acc[blk][r] = bf2f(G0[((size_t)(b0 + q * 4 + r) * 512 + t) * 1024 + nidx[blk]]);
    } else {
#pragma unroll
      for (int blk = 0; blk < 8; ++blk)
        acc[blk] = (floatx4){bc0v[blk], bc0v[blk], bc0v[blk], bc0v[blk]};
      short8 axf[4];
#pragma unroll
      for (int kt = 0; kt < 4; ++kt) axf[kt] = *(const short8*)(xrow + (size_t)t * 128 + kt * 32);
#pragma unroll
      for (int blk = 0; blk < 8; ++blk) {
        const unsigned short* wp = Wc + (size_t)nidx[blk] * 128 + q * 8;
        floatx4 a = acc[blk];
#pragma unroll
        for (int kt = 0; kt < 4; ++kt) a = mfma16(axf[kt], *(const short8*)(wp + kt * 32), a);
        acc[blk] = a;
      }
    }
#pragma unroll
    for (int blk = 0; blk < 8; ++blk) {
      const unsigned short* wp = Whh0 + (size_t)nidx[blk] * 256 + q * 8;
      floatx4 a = acc[blk];
#pragma unroll
      for (int kt = 0; kt < 8; ++kt) a = mfma16(a0f[kt], *(const short8*)(wp + kt * 32), a);
      acc[blk] = a;
    }
    // cell0
    float h0v[8];
#pragma unroll
    for (int s2 = 0; s2 < 2; ++s2)
#pragma unroll
      for (int r = 0; r < 4; ++r) {
        const float iv = acc[s2 * 4 + 0][r], fv = acc[s2 * 4 + 1][r];
        const float gv = acc[s2 * 4 + 2][r], ov = acc[s2 * 4 + 3][r];
        const float cn = sigm(fv) * cst0[s2][r] + sigm(iv) * tanh_fast(gv);
        cst0[s2][r] = cn;
        h0v[s2 * 4 + r] = sigm(ov) * tanh_fast(cn);
      }
    __syncthreads();
#pragma unroll
    for (int s2 = 0; s2 < 2; ++s2)
#pragma unroll
      for (int r = 0; r < 4; ++r)
        h0buf[(q * 4 + r) * 264 + c * 64 + (2 * sh + s2) * 16 + lm] = f2bf(h0v[s2 * 4 + r]);
    __syncthreads();

    // ---- layer1: gates = h0_t @ Wih1^T + h1 @ Whh1^T + b1 ----
    short8 a0n[8], a1f[8];
#pragma unroll
    for (int kt = 0; kt < 8; ++kt) {
      a0n[kt] = *(const short8*)&h0buf[lm * 264 + kt * 32 + q * 8];
      a1f[kt] = *(const short8*)&h1buf[lm * 264 + kt * 32 + q * 8];
    }
#pragma unroll
    for (int blk = 0; blk < 8; ++blk) {
      const unsigned short* wpi = Wih1 + (size_t)nidx[blk] * 256 + q * 8;
      const unsigned short* wph = Whh1 + (size_t)nidx[blk] * 256 + q * 8;
      floatx4 a = (floatx4){b1v[blk], b1v[blk], b1v[blk], b1v[blk]};
#pragma unroll
      for (int kt = 0; kt < 8; ++kt) a = mfma16(a0n[kt], *(const short8*)(wpi + kt * 32), a);
#pragma unroll
      for (int kt = 0; kt < 8; ++kt) a = mfma16(a1f[kt], *(const short8*)(wph + kt * 32), a);
      acc[blk] = a;
    }
    // cell1
    float h1v[8];
#pragma unroll
    for (int s2 = 0; s2 < 2; ++s2)
#pragma unroll
      for (int r = 0; r < 4; ++r) {
        const float iv = acc[s2 * 4 + 0][r], fv = acc[s2 * 4 + 1][r];
        const float gv = acc[s2 * 4 + 2][r], ov = acc[s2 * 4 + 3][r];
        const float cn = sigm(fv) * cst1[s2][r] + sigm(iv) * tanh_fast(gv);
        cst1[s2][r] = cn;
        h1v[s2 * 4 + r] = sigm(ov) * tanh_fast(cn);
      }
    __syncthreads();
#pragma unroll
    for (int s2 = 0; s2 < 2; ++s2)
#pragma unroll
      for (int r = 0; r < 4; ++r)
        h1buf[(q * 4 + r) * 264 + c * 64 + (2 * sh + s2) * 16 + lm] = f2bf(h1v[s2 * 4 + r]);
    __syncthreads();

    // ---- attn: total_t = h1_t @ tahW^T + tahb (wave's f-tile = fb) ----
    short8 a1n[8];
#pragma unroll
    for (int kt = 0; kt < 8; ++kt) a1n[kt] = *(const short8*)&h1buf[lm * 264 + kt * 32 + q * 8];
    floatx4 ta = (floatx4){tahbv, tahbv, tahbv, tahbv};
#pragma unroll
    for (int kt = 0; kt < 8; ++kt)
      ta = mfma16(a1n[kt], *(const short8*)&tahWs[(fb + lm) * 264 + kt * 32 + q * 8], ta);
#pragma unroll
    for (int r = 0; r < 4; ++r) totB[(q * 4 + r) * 136 + fb + lm] = f2bf(ta[r]);
    __syncthreads();
    // spre = relu(total @ taW^T + tab); accumulate softmax-over-t numer/denom
    short8 atf[4];
#pragma unroll
    for (int kt = 0; kt < 4; ++kt) atf[kt] = *(const short8*)&totB[lm * 136 + kt * 32 + q * 8];
    floatx4 sa = (floatx4){tabv, tabv, tabv, tabv};
#pragma unroll
    for (int kt = 0; kt < 4; ++kt)
      sa = mfma16(atf[kt], *(const short8*)&taWs[(fb + lm) * 136 + kt * 32 + q * 8], sa);
#pragma unroll
    for (int r = 0; r < 4; ++r) {
      const float e = __expf(fmaxf(sa[r], 0.f));  // spre in [0,~1]: no overflow
      num[r] += e * ta[r];  // ta[r] == total at (row q*4+r, col fcol), same C-layout
      den[r] += e;
    }
    __syncthreads();  // totB reads done before next-step overwrite path
  }

  // ---- out[b] = sum_f (num/den)*outW ----
#pragma unroll
  for (int r = 0; r < 4; ++r) red[(q * 4 + r) * 136 + fcol] = (num[r] / den[r]) * outWv;
  __syncthreads();
  if (tid < 16) {
    float s = 0.f;
    for (int k = 0; k < 128; ++k) s += red[tid * 136 + k];
    out[b0 + tid] = s;
  }
}

// ---------- host ----------
extern "C" void kernel_launch(void* const* d_in, const int* in_sizes, int n_in,
                              void* d_out, int out_size, void* d_ws, size_t ws_size,
                              hipStream_t stream) {
  (void)in_sizes; (void)n_in; (void)out_size;
  const float* x    = (const float*)d_in[0];
  const float* bng  = (const float*)d_in[1];
  const float* bnb  = (const float*)d_in[2];
  const float* bnm  = (const float*)d_in[3];
  const float* bnv  = (const float*)d_in[4];
  const float* saW  = (const float*)d_in[5];
  const float* sab  = (const float*)d_in[6];
  const float* inW  = (const float*)d_in[7];
  const float* inb  = (const float*)d_in[8];
  const float* Wih0 = (const float*)d_in[9];
  const float* Whh0 = (const float*)d_in[10];
  const float* bih0 = (const float*)d_in[11];
  const float* bhh0 = (const float*)d_in[12];
  const float* Wih1 = (const float*)d_in[13];
  const float* Whh1 = (const float*)d_in[14];
  const float* bih1 = (const float*)d_in[15];
  const float* bhh1 = (const float*)d_in[16];
  const float* tahW = (const float*)d_in[17];
  const float* tahb = (const float*)d_in[18];
  const float* taW  = (const float*)d_in[19];
  const float* tab  = (const float*)d_in[20];
  const float* outW = (const float*)d_in[21];
  float* out = (float*)d_out;

  char* ws = (char*)d_ws;
  size_t off = 0;
  auto alloc = [&](size_t bytes) {
    char* p = ws + off;
    off += (bytes + 255) & ~(size_t)255;
    return p;
  };
  unsigned short* Wc    = (unsigned short*)alloc((size_t)1024 * 128 * 2);
  float* bc             = (float*)alloc(1024 * 4);
  float* b1             = (float*)alloc(1024 * 4);
  unsigned short* Whh0b = (unsigned short*)alloc((size_t)1024 * 256 * 2);
  unsigned short* Whh1b = (unsigned short*)alloc((size_t)1024 * 256 * 2);
  unsigned short* Wih1b = (unsigned short*)alloc((size_t)1024 * 256 * 2);
  unsigned short* tahWb = (unsigned short*)alloc((size_t)128 * 256 * 2);
  unsigned short* taWb  = (unsigned short*)alloc((size_t)128 * 128 * 2);
  unsigned short* xs    = (unsigned short*)alloc((size_t)131072 * 128 * 2);

  const size_t g0B = (size_t)131072 * 1024 * 2;  // 268 MB bf16
  const int useG = (off + g0B + 4096) <= ws_size;
  unsigned short* G0 = useG ? (unsigned short*)alloc(g0B) : nullptr;

  hipLaunchKernelGGL(wc_kernel, dim3(1024), dim3(128), 0, stream, Wih0, inW, inb, bih0, bhh0, Wc, bc);
  hipLaunchKernelGGL(cvt_kernel, dim3(1024), dim3(256), 0, stream, Whh0b, Whh0, 262144);
  hipLaunchKernelGGL(cvt_kernel, dim3(1024), dim3(256), 0, stream, Whh1b, Whh1, 262144);
  hipLaunchKernelGGL(cvt_kernel, dim3(1024), dim3(256), 0, stream, Wih1b, Wih1, 262144);
  hipLaunchKernelGGL(cvt_kernel, dim3(128), dim3(256), 0, stream, tahWb, tahW, 32768);
  hipLaunchKernelGGL(cvt_kernel, dim3(64), dim3(256), 0, stream, taWb, taW, 16384);
  hipLaunchKernelGGL(addb_kernel, dim3(4), dim3(256), 0, stream, b1, bih1, bhh1, 1024);
  hipLaunchKernelGGL(bnsa_kernel, dim3(1024), dim3(128), 0, stream, x, bng, bnb, bnm, bnv, saW, sab, xs, 128);

  if (useG) {
    hipLaunchKernelGGL(gemm_bt, dim3(1024, 8), dim3(256), 0, stream, xs, Wc, bc,
                       (float*)nullptr, G0, 131072, 1024, 128, 0);
  }
  hipLaunchKernelGGL(mega8_kernel, dim3(16), dim3(512), 0, stream, xs, G0, Wc, bc, Whh0b, Wih1b,
                     b1, Whh1b, tahWb, tahb, taWb, tab, outW, out);
}

// Round 4
// 10298.100 us; speedup vs baseline: 2.7578x; 2.6341x over previous
//
#include <hip/hip_runtime.h>

typedef __attribute__((ext_vector_type(8))) short short8;
typedef __attribute__((ext_vector_type(4))) float floatx4;

// ---------- helpers ----------
__device__ __forceinline__ unsigned short f2bf(float f) {
  unsigned int u = __float_as_uint(f);
  unsigned int lsb = (u >> 16) & 1u;
  u += 0x7fffu + lsb;  // round-to-nearest-even
  return (unsigned short)(u >> 16);
}
__device__ __forceinline__ float bf2f(unsigned short u) {
  unsigned int x = ((unsigned int)u) << 16;
  return __uint_as_float(x);
}
__device__ __forceinline__ float sigm(float x) { return 1.f / (1.f + __expf(-x)); }
__device__ __forceinline__ float tanh_fast(float x) { return 2.f / (1.f + __expf(-2.f * x)) - 1.f; }
__device__ __forceinline__ floatx4 mfma16(short8 a, short8 b, floatx4 c) {
  return __builtin_amdgcn_mfma_f32_16x16x32_bf16(a, b, c, 0, 0, 0);
}

// ---------- prep ----------
__global__ void wc_kernel(const float* __restrict__ Wih0, const float* __restrict__ inW,
                          const float* __restrict__ inb, const float* __restrict__ bih0,
                          const float* __restrict__ bhh0, unsigned short* __restrict__ Wc,
                          float* __restrict__ bc) {
  const int n = blockIdx.x;   // 0..1023
  const int k = threadIdx.x;  // 0..127
  float a = 0.f;
  for (int j = 0; j < 256; ++j) a += Wih0[n * 256 + j] * inW[j * 128 + k];
  Wc[n * 128 + k] = f2bf(a);
  if (k == 0) {
    float bsum = bih0[n] + bhh0[n];
    for (int j = 0; j < 256; ++j) bsum += Wih0[n * 256 + j] * inb[j];
    bc[n] = bsum;
  }
}

__global__ void cvt_kernel(unsigned short* __restrict__ dst, const float* __restrict__ src, int n) {
  int i = blockIdx.x * 256 + threadIdx.x;
  if (i < n) dst[i] = f2bf(src[i]);
}

__global__ void addb_kernel(float* __restrict__ b1, const float* __restrict__ xa,
                            const float* __restrict__ ya, int n) {
  int i = blockIdx.x * 256 + threadIdx.x;
  if (i < n) b1[i] = xa[i] + ya[i];
}

// ---------- BatchNorm + spatial attention ----------
__global__ __launch_bounds__(128) void bnsa_kernel(
    const float* __restrict__ x, const float* __restrict__ gamma,
    const float* __restrict__ beta, const float* __restrict__ mean,
    const float* __restrict__ var, const float* __restrict__ saW,
    const float* __restrict__ sab, unsigned short* __restrict__ xs, int rowsPerWg) {
  __shared__ unsigned short saT[128 * 128];  // bf16 [k][j] = saW[j][k]
  __shared__ float xbuf[128];
  __shared__ float ebuf[128];
  const int j = threadIdx.x;
  for (int k = 0; k < 128; ++k) saT[k * 128 + j] = f2bf(saW[j * 128 + k]);
  const float g = gamma[j], bt = beta[j], mn = mean[j];
  const float istd = rsqrtf(var[j] + 1e-5f);
  const float sb = sab[j];
  __syncthreads();
  const long row0 = (long)blockIdx.x * rowsPerWg;
  for (int it = 0; it < rowsPerWg; ++it) {
    const long row = row0 + it;
    const float xv = x[row * 128 + j];
    const float xb = (xv - mn) * istd * g + bt;
    xbuf[j] = xb;
    __syncthreads();
    float s = sb;
#pragma unroll 8
    for (int k = 0; k < 128; ++k) s += xbuf[k] * bf2f(saT[k * 128 + j]);
    const float e = __expf(sigm(s));
    ebuf[j] = e;
    __syncthreads();
    float sum = 0.f;
#pragma unroll 8
    for (int k = 0; k < 128; ++k) sum += ebuf[k];
    xs[row * 128 + j] = f2bf(xb * (e / sum));
    __syncthreads();
  }
}

// ---------- N-split persistent kernel ----------
// 128 wgs = 16 batch-groups x 8 slices; 512 thr (8 waves).
// Wave wv: gate g=wv&3 of hidden tile ht=wv>>2 (global hidden cols slice*32+ht*16+..),
// i.e. gate row ng = g*256 + slice*32 + ht*16 + lm. Weights for that row are VGPR-resident
// B-frags, loaded ONCE. Attention (f-col wv*16+lm) weights LDS-resident; attn replicated
// per wg so only h0/h1 need cross-wg exchange (8KB/group, double-buffered, flag-synced).
__global__ __launch_bounds__(512, 2) void persist_kernel(
    const unsigned short* __restrict__ xs,  // [B,T,128] bf16
    const unsigned short* __restrict__ Wc, const float* __restrict__ bc,
    const unsigned short* __restrict__ Whh0,
    const unsigned short* __restrict__ Wih1, const float* __restrict__ b1,
    const unsigned short* __restrict__ Whh1,
    const unsigned short* __restrict__ tahWg, const float* __restrict__ tahb,
    const unsigned short* __restrict__ taWg, const float* __restrict__ tab,
    const float* __restrict__ outW,
    unsigned short* __restrict__ ex0, unsigned short* __restrict__ ex1,
    int* __restrict__ flags, float* __restrict__ out) {
  __shared__ unsigned short tahWs[128 * 264];  // [f][k], k<256
  __shared__ unsigned short taWs[128 * 136];   // [f][j], j<128
  __shared__ unsigned short h0buf[16 * 264];   // full h0 for this batch group
  __shared__ unsigned short h1buf[16 * 264];
  __shared__ float gatebuf[8 * 16 * 17];       // [gateblk][m][n] (reused as final red)
  __shared__ unsigned short totB[16 * 136];

  const int tid = threadIdx.x;
  const int wv = tid >> 6, lane = tid & 63;
  const int lm = lane & 15, q = lane >> 4;
  const int slice = blockIdx.x >> 4, group = blockIdx.x & 15;
  const int g = wv & 3, ht = wv >> 2;
  const int b0 = group * 16;
  const int hcol = slice * 32 + ht * 16 + lm;  // hidden col of this wave's block
  const int ng = g * 256 + hcol;               // gate row (torch i,f,g,o order)
  const int fcol = wv * 16 + lm;               // attention f-col

  for (int i = tid; i < 128 * 256; i += 512) tahWs[(i >> 8) * 264 + (i & 255)] = tahWg[i];
  for (int i = tid; i < 128 * 128; i += 512) taWs[(i >> 7) * 136 + (i & 127)] = taWg[i];
  for (int i = tid; i < 16 * 264; i += 512) { h0buf[i] = 0; h1buf[i] = 0; }

  // register-resident weight B-frags (loaded once)
  short8 Wcf[4], W0f[8], W1if[8], W1hf[8];
#pragma unroll
  for (int kt = 0; kt < 4; ++kt) Wcf[kt] = *(const short8*)&Wc[(size_t)ng * 128 + kt * 32 + q * 8];
#pragma unroll
  for (int kt = 0; kt < 8; ++kt) {
    W0f[kt] = *(const short8*)&Whh0[(size_t)ng * 256 + kt * 32 + q * 8];
    W1if[kt] = *(const short8*)&Wih1[(size_t)ng * 256 + kt * 32 + q * 8];
    W1hf[kt] = *(const short8*)&Whh1[(size_t)ng * 256 + kt * 32 + q * 8];
  }
  const float bcv = bc[ng], b1v = b1[ng];
  const float tahbv = tahb[fcol], tabv = tab[fcol], outWv = outW[fcol];

  floatx4 cst0 = (floatx4){0.f, 0.f, 0.f, 0.f};
  floatx4 cst1 = (floatx4){0.f, 0.f, 0.f, 0.f};
  float num[4] = {0.f, 0.f, 0.f, 0.f}, den[4] = {0.f, 0.f, 0.f, 0.f};

  const unsigned short* xrow = xs + (size_t)(b0 + lm) * 65536 + q * 8;
  short8 axf[4], axn[4];
#pragma unroll
  for (int kt = 0; kt < 4; ++kt) axf[kt] = *(const short8*)(xrow + kt * 32);

  const int exm = tid >> 5, exc = (tid & 31) * 8;  // exchange-read assignment
  __syncthreads();

  for (int t = 0; t < 512; ++t) {
    const int p = t & 1;
    const size_t exoff = ((size_t)p * 16 + group) * (16 * 256);

    // ---- phase A: gates0 = xs_t @ Wc^T + h0 @ Whh0^T + bc (this wave's 16 rows) ----
    floatx4 acc = (floatx4){bcv, bcv, bcv, bcv};
#pragma unroll
    for (int kt = 0; kt < 4; ++kt) acc = mfma16(axf[kt], Wcf[kt], acc);
#pragma unroll
    for (int kt = 0; kt < 8; ++kt) {
      const short8 a = *(const short8*)&h0buf[lm * 264 + kt * 32 + q * 8];
      acc = mfma16(a, W0f[kt], acc);
    }
#pragma unroll
    for (int r = 0; r < 4; ++r) gatebuf[(wv * 16 + q * 4 + r) * 17 + lm] = acc[r];
    // prefetch next xs frags under the sync/exchange latency
    {
      const size_t tn = (t < 511) ? t + 1 : t;
#pragma unroll
      for (int kt = 0; kt < 4; ++kt) axn[kt] = *(const short8*)(xrow + tn * 128 + kt * 32);
    }
    __syncthreads();

    // ---- phase B: cell0 (waves 0,4), publish h0 slice ----
    if (g == 0) {
#pragma unroll
      for (int r = 0; r < 4; ++r) {
        const int m = q * 4 + r;
        const float iv = gatebuf[((ht * 4 + 0) * 16 + m) * 17 + lm];
        const float fv = gatebuf[((ht * 4 + 1) * 16 + m) * 17 + lm];
        const float gv = gatebuf[((ht * 4 + 2) * 16 + m) * 17 + lm];
        const float ov = gatebuf[((ht * 4 + 3) * 16 + m) * 17 + lm];
        const float cn = sigm(fv) * cst0[r] + sigm(iv) * tanh_fast(gv);
        cst0[r] = cn;
        ex0[exoff + m * 256 + hcol] = f2bf(sigm(ov) * tanh_fast(cn));
      }
      __threadfence();
    }
    __syncthreads();
    if (tid == 0)
      __hip_atomic_store(&flags[p * 128 + group * 8 + slice], t + 1, __ATOMIC_RELEASE,
                         __HIP_MEMORY_SCOPE_AGENT);
    if (tid < 8) {
      while (__hip_atomic_load(&flags[p * 128 + group * 8 + tid], __ATOMIC_ACQUIRE,
                               __HIP_MEMORY_SCOPE_AGENT) < t + 1) {}
    }
    __syncthreads();
    *(short8*)&h0buf[exm * 264 + exc] = *(const short8*)&ex0[exoff + exm * 256 + exc];
    __syncthreads();

    // ---- phase D: gates1 = h0_t @ Wih1^T + h1 @ Whh1^T + b1 ----
    floatx4 acc1 = (floatx4){b1v, b1v, b1v, b1v};
#pragma unroll
    for (int kt = 0; kt < 8; ++kt) {
      const short8 a = *(const short8*)&h0buf[lm * 264 + kt * 32 + q * 8];
      acc1 = mfma16(a, W1if[kt], acc1);
    }
#pragma unroll
    for (int kt = 0; kt < 8; ++kt) {
      const short8 a = *(const short8*)&h1buf[lm * 264 + kt * 32 + q * 8];
      acc1 = mfma16(a, W1hf[kt], acc1);
    }
#pragma unroll
    for (int r = 0; r < 4; ++r) gatebuf[(wv * 16 + q * 4 + r) * 17 + lm] = acc1[r];
    __syncthreads();

    // ---- phase E: cell1, publish h1 slice ----
    if (g == 0) {
#pragma unroll
      for (int r = 0; r < 4; ++r) {
        const int m = q * 4 + r;
        const float iv = gatebuf[((ht * 4 + 0) * 16 + m) * 17 + lm];
        const float fv = gatebuf[((ht * 4 + 1) * 16 + m) * 17 + lm];
        const float gv = gatebuf[((ht * 4 + 2) * 16 + m) * 17 + lm];
        const float ov = gatebuf[((ht * 4 + 3) * 16 + m) * 17 + lm];
        const float cn = sigm(fv) * cst1[r] + sigm(iv) * tanh_fast(gv);
        cst1[r] = cn;
        ex1[exoff + m * 256 + hcol] = f2bf(sigm(ov) * tanh_fast(cn));
      }
      __threadfence();
    }
    __syncthreads();
    if (tid == 0)
      __hip_atomic_store(&flags[256 + p * 128 + group * 8 + slice], t + 1, __ATOMIC_RELEASE,
                         __HIP_MEMORY_SCOPE_AGENT);
    if (tid < 8) {
      while (__hip_atomic_load(&flags[256 + p * 128 + group * 8 + tid], __ATOMIC_ACQUIRE,
                               __HIP_MEMORY_SCOPE_AGENT) < t + 1) {}
    }
    __syncthreads();
    *(short8*)&h1buf[exm * 264 + exc] = *(const short8*)&ex1[exoff + exm * 256 + exc];
    __syncthreads();

    // ---- phase F: attention (replicated per wg; wave's f-tile = fcol) ----
    floatx4 ta = (floatx4){tahbv, tahbv, tahbv, tahbv};
#pragma unroll
    for (int kt = 0; kt < 8; ++kt) {
      const short8 a = *(const short8*)&h1buf[lm * 264 + kt * 32 + q * 8];
      ta = mfma16(a, *(const short8*)&tahWs[fcol * 264 + kt * 32 + q * 8], ta);
    }
#pragma unroll
    for (int r = 0; r < 4; ++r) totB[(q * 4 + r) * 136 + fcol] = f2bf(ta[r]);
    __syncthreads();
    floatx4 sa = (floatx4){tabv, tabv, tabv, tabv};
#pragma unroll
    for (int kt = 0; kt < 4; ++kt) {
      const short8 a = *(const short8*)&totB[lm * 136 + kt * 32 + q * 8];
      sa = mfma16(a, *(const short8*)&taWs[fcol * 136 + kt * 32 + q * 8], sa);
    }
#pragma unroll
    for (int r = 0; r < 4; ++r) {
      const float e = __expf(fmaxf(sa[r], 0.f));  // relu(spre) in [0,~1]: safe
      num[r] += e * ta[r];
      den[r] += e;
    }
    __syncthreads();  // totB reads done before next step's writes

#pragma unroll
    for (int kt = 0; kt < 4; ++kt) axf[kt] = axn[kt];
  }

  // ---- out[b] = sum_f (num/den)*outW ----
  float* red = gatebuf;  // 16*136 = 2176 floats fits exactly
#pragma unroll
  for (int r = 0; r < 4; ++r) red[(q * 4 + r) * 136 + fcol] = (num[r] / den[r]) * outWv;
  __syncthreads();
  if (slice == 0 && tid < 16) {
    float s = 0.f;
    for (int k = 0; k < 128; ++k) s += red[tid * 136 + k];
    out[b0 + tid] = s;
  }
}

// ---------- host ----------
extern "C" void kernel_launch(void* const* d_in, const int* in_sizes, int n_in,
                              void* d_out, int out_size, void* d_ws, size_t ws_size,
                              hipStream_t stream) {
  (void)in_sizes; (void)n_in; (void)out_size; (void)ws_size;
  const float* x    = (const float*)d_in[0];
  const float* bng  = (const float*)d_in[1];
  const float* bnb  = (const float*)d_in[2];
  const float* bnm  = (const float*)d_in[3];
  const float* bnv  = (const float*)d_in[4];
  const float* saW  = (const float*)d_in[5];
  const float* sab  = (const float*)d_in[6];
  const float* inW  = (const float*)d_in[7];
  const float* inb  = (const float*)d_in[8];
  const float* Wih0 = (const float*)d_in[9];
  const float* Whh0 = (const float*)d_in[10];
  const float* bih0 = (const float*)d_in[11];
  const float* bhh0 = (const float*)d_in[12];
  const float* Wih1 = (const float*)d_in[13];
  const float* Whh1 = (const float*)d_in[14];
  const float* bih1 = (const float*)d_in[15];
  const float* bhh1 = (const float*)d_in[16];
  const float* tahW = (const float*)d_in[17];
  const float* tahb = (const float*)d_in[18];
  const float* taW  = (const float*)d_in[19];
  const float* tab  = (const float*)d_in[20];
  const float* outW = (const float*)d_in[21];
  float* out = (float*)d_out;

  char* ws = (char*)d_ws;
  size_t off = 0;
  auto alloc = [&](size_t bytes) {
    char* p = ws + off;
    off += (bytes + 255) & ~(size_t)255;
    return p;
  };
  unsigned short* Wc    = (unsigned short*)alloc((size_t)1024 * 128 * 2);
  float* bc             = (float*)alloc(1024 * 4);
  float* b1             = (float*)alloc(1024 * 4);
  unsigned short* Whh0b = (unsigned short*)alloc((size_t)1024 * 256 * 2);
  unsigned short* Whh1b = (unsigned short*)alloc((size_t)1024 * 256 * 2);
  unsigned short* Wih1b = (unsigned short*)alloc((size_t)1024 * 256 * 2);
  unsigned short* tahWb = (unsigned short*)alloc((size_t)128 * 256 * 2);
  unsigned short* taWb  = (unsigned short*)alloc((size_t)128 * 128 * 2);
  unsigned short* xs    = (unsigned short*)alloc((size_t)131072 * 128 * 2);
  unsigned short* ex0   = (unsigned short*)alloc((size_t)2 * 16 * 16 * 256 * 2);
  unsigned short* ex1   = (unsigned short*)alloc((size_t)2 * 16 * 16 * 256 * 2);
  int* flags            = (int*)alloc(512 * 4);

  hipMemsetAsync(flags, 0, 512 * 4, stream);
  hipLaunchKernelGGL(wc_kernel, dim3(1024), dim3(128), 0, stream, Wih0, inW, inb, bih0, bhh0, Wc, bc);
  hipLaunchKernelGGL(cvt_kernel, dim3(1024), dim3(256), 0, stream, Whh0b, Whh0, 262144);
  hipLaunchKernelGGL(cvt_kernel, dim3(1024), dim3(256), 0, stream, Whh1b, Whh1, 262144);
  hipLaunchKernelGGL(cvt_kernel, dim3(1024), dim3(256), 0, stream, Wih1b, Wih1, 262144);
  hipLaunchKernelGGL(cvt_kernel, dim3(128), dim3(256), 0, stream, tahWb, tahW, 32768);
  hipLaunchKernelGGL(cvt_kernel, dim3(64), dim3(256), 0, stream, taWb, taW, 16384);
  hipLaunchKernelGGL(addb_kernel, dim3(4), dim3(256), 0, stream, b1, bih1, bhh1, 1024);
  hipLaunchKernelGGL(bnsa_kernel, dim3(1024), dim3(128), 0, stream, x, bng, bnb, bnm, bnv, saW, sab, xs, 128);
  hipLaunchKernelGGL(persist_kernel, dim3(128), dim3(512), 0, stream, xs, Wc, bc, Whh0b, Wih1b,
                     b1, Whh1b, tahWb, tahb, taWb, tab, outW, ex0, ex1, flags, out);
}